// Round 1
// baseline (260.402 us; speedup 1.0000x reference)
//
#include <hip/hip_runtime.h>
#include <stdint.h>
#include <stddef.h>

// DynamicRouter: logits = x @ W^T / T; top-2; softmax; scatter.
// B=8192, D=4096, E=64, K=2.
// Strategy: split-bf16 (hi/lo) 4-term MFMA GEMM, no-LDS main loop,
// pre-swizzled W fragments in d_ws, fused top-2 + softmax + scatter epilogue.

typedef __attribute__((ext_vector_type(8))) short short8;   // 8 bf16 (4 VGPRs)
typedef __attribute__((ext_vector_type(4))) float f32x4;    // MFMA accumulator

static constexpr int kB = 8192;
static constexpr int kD = 4096;
static constexpr int kE = 64;
static constexpr int kSteps = kD / 32;   // 128 K-steps of 32

__device__ __forceinline__ uint32_t bf16_rne(float v) {
    uint32_t u = __builtin_bit_cast(uint32_t, v);
    return (u + 0x7FFFu + ((u >> 16) & 1u)) >> 16;
}

// Split gate_w fp32 -> bf16 hi/lo in MFMA-B-fragment-swizzled layout:
// chunk index ((ntile*128 + s)*64 + lane) holds, for lane l:
//   w[e = ntile*16 + (l&15)][k = s*32 + (l>>4)*8 + j], j=0..7  (16 B contiguous)
__global__ __launch_bounds__(256) void prep_w_kernel(
    const float* __restrict__ w, short* __restrict__ w_hi, short* __restrict__ w_lo)
{
    int tid  = blockIdx.x * 256 + threadIdx.x;   // 0..32767
    int lane = tid & 63;
    int s    = (tid >> 6) & (kSteps - 1);
    int nt   = tid >> 13;                        // 0..3
    int e = nt * 16 + (lane & 15);
    int k = s * 32 + (lane >> 4) * 8;
    const float* src = w + (size_t)e * kD + k;
    short8 hi, lo;
#pragma unroll
    for (int j = 0; j < 8; ++j) {
        float xv = src[j];
        uint32_t u  = __builtin_bit_cast(uint32_t, xv);
        uint32_t rh = (u + 0x7FFFu + ((u >> 16) & 1u)) & 0xFFFF0000u;
        hi[j] = (short)(rh >> 16);
        float lf = xv - __builtin_bit_cast(float, rh);   // exact residual
        lo[j] = (short)bf16_rne(lf);
    }
    ((short8*)w_hi)[tid] = hi;
    ((short8*)w_lo)[tid] = lo;
}

// Block: 16 rows of x, all 64 experts. 4 waves; wave w owns expert tile w (16 cols).
// Grid: 8192/16 = 512 blocks (2 blocks/CU -> 2 waves/SIMD).
__global__ __launch_bounds__(256, 2) void router_kernel(
    const float* __restrict__ x, const short8* __restrict__ w_hi,
    const short8* __restrict__ w_lo, const float* __restrict__ temp,
    float* __restrict__ out_mat, float* __restrict__ out_idx)
{
    const int lane = threadIdx.x & 63;
    const int wv   = threadIdx.x >> 6;   // N-tile 0..3
    const int quad = lane >> 4;
    const int mr   = lane & 15;
    const int row0 = blockIdx.x * 16;

    // A frag: lane holds x[row0+mr][s*32 + quad*8 .. +8]  (A[m=lane&15][k=quad*8+j])
    const float* xp = x + (size_t)(row0 + mr) * kD + quad * 8;
    const short8* bh = w_hi + (size_t)(wv * kSteps) * 64 + lane;
    const short8* bl = w_lo + (size_t)(wv * kSteps) * 64 + lane;

    f32x4 acc = {0.f, 0.f, 0.f, 0.f};

#pragma unroll 4
    for (int s = 0; s < kSteps; ++s) {
        const f32x4* ap = (const f32x4*)(xp + s * 32);
        f32x4 a0 = ap[0];
        f32x4 a1 = ap[1];
        short8 wh = bh[(size_t)s * 64];
        short8 wl = bl[(size_t)s * 64];
        short8 ah, al;
#pragma unroll
        for (int j = 0; j < 4; ++j) {
            float xv = a0[j];
            uint32_t u  = __builtin_bit_cast(uint32_t, xv);
            uint32_t rh = (u + 0x7FFFu + ((u >> 16) & 1u)) & 0xFFFF0000u;
            ah[j] = (short)(rh >> 16);
            al[j] = (short)bf16_rne(xv - __builtin_bit_cast(float, rh));
            float yv = a1[j];
            uint32_t u2  = __builtin_bit_cast(uint32_t, yv);
            uint32_t rh2 = (u2 + 0x7FFFu + ((u2 >> 16) & 1u)) & 0xFFFF0000u;
            ah[j + 4] = (short)(rh2 >> 16);
            al[j + 4] = (short)bf16_rne(yv - __builtin_bit_cast(float, rh2));
        }
        // smallest terms first to minimize accumulation-order error
        acc = __builtin_amdgcn_mfma_f32_16x16x32_bf16(al, wl, acc, 0, 0, 0);
        acc = __builtin_amdgcn_mfma_f32_16x16x32_bf16(al, wh, acc, 0, 0, 0);
        acc = __builtin_amdgcn_mfma_f32_16x16x32_bf16(ah, wl, acc, 0, 0, 0);
        acc = __builtin_amdgcn_mfma_f32_16x16x32_bf16(ah, wh, acc, 0, 0, 0);
    }

    // Epilogue: C layout (m89-verified): row = quad*4 + reg, col = lane&15.
    __shared__ float lg[16][65];
    __shared__ int   si1[16], si2[16];
    __shared__ float sw1[16], sw2[16];

    {
        const int col = wv * 16 + mr;
#pragma unroll
        for (int r = 0; r < 4; ++r)
            lg[quad * 4 + r][col] = acc[r];
    }
    __syncthreads();

    if (threadIdx.x < 16) {
        const int t = threadIdx.x;
        float v1 = -3.0e38f, v2 = -3.0e38f;
        int i1 = 0, i2 = 0;
        for (int j = 0; j < 64; ++j) {
            float v = lg[t][j];
            if (v > v1)      { v2 = v1; i2 = i1; v1 = v; i1 = j; }  // strict > = jax tie-break
            else if (v > v2) { v2 = v;  i2 = j; }
        }
        float invT = 1.0f / temp[0];
        float e  = expf((v2 - v1) * invT);   // exp(l2/T - l1/T), max-subtracted like jax
        float sm = 1.0f + e;
        float w1 = 1.0f / sm;
        float w2 = e / sm;
        si1[t] = i1; si2[t] = i2; sw1[t] = w1; sw2[t] = w2;
        // top_idx stored as float values (whole d_out read back as fp32)
        float2 iv = make_float2((float)i1, (float)i2);
        ((float2*)out_idx)[row0 + t] = iv;
    }
    __syncthreads();

    {   // coalesced routing-matrix write: 256 thr x 1 float4 = 16 rows x 64 cols
        const int t  = threadIdx.x;
        const int r  = t >> 4;
        const int c0 = (t & 15) * 4;
        const int i1 = si1[r], i2 = si2[r];
        const float w1 = sw1[r], w2 = sw2[r];
        f32x4 o;
#pragma unroll
        for (int j = 0; j < 4; ++j) {
            int c = c0 + j;
            o[j] = (c == i1) ? w1 : ((c == i2) ? w2 : 0.0f);
        }
        *(f32x4*)(out_mat + (size_t)(row0 + r) * kE + c0) = o;
    }
}

extern "C" void kernel_launch(void* const* d_in, const int* in_sizes, int n_in,
                              void* d_out, int out_size, void* d_ws, size_t ws_size,
                              hipStream_t stream) {
    const float* x    = (const float*)d_in[0];
    const float* gw   = (const float*)d_in[1];
    const float* temp = (const float*)d_in[2];

    float* out_mat = (float*)d_out;                      // [8192,64] fp32
    float* out_idx = (float*)d_out + (size_t)kB * kE;    // [8192,2] idx as float

    short* w_hi = (short*)d_ws;                          // 512 KB
    short* w_lo = w_hi + (size_t)kE * kD;                // 512 KB

    prep_w_kernel<<<128, 256, 0, stream>>>(gw, w_hi, w_lo);

    router_kernel<<<kB / 16, 256, 0, stream>>>(
        x, (const short8*)w_hi, (const short8*)w_lo, temp, out_mat, out_idx);
}

// Round 2
// 218.563 us; speedup vs baseline: 1.1914x; 1.1914x over previous
//
#include <hip/hip_runtime.h>
#include <stdint.h>
#include <stddef.h>

// DynamicRouter: logits = x @ W^T / T; top-2; softmax; scatter.
// B=8192, D=4096, E=64, K=2.
// R2: K-split across 16 waves/block (1024 thr) for occupancy; each wave owns
// all 4 expert tiles (x converted once, not 4x); LDS partial reduction lands
// row-per-wave -> shuffle-butterfly top-2 epilogue.

typedef __attribute__((ext_vector_type(8))) short short8;   // 8 bf16 (4 VGPRs)
typedef __attribute__((ext_vector_type(4))) float f32x4;    // MFMA accumulator

static constexpr int kB = 8192;
static constexpr int kD = 4096;
static constexpr int kE = 64;
static constexpr int kSteps = kD / 32;            // 128 K-steps of 32
static constexpr int kChunks = 16;                // waves per block = K-chunks
static constexpr int kStepsPerChunk = kSteps / kChunks;  // 8

__device__ __forceinline__ uint32_t bf16_rne(float v) {
    uint32_t u = __builtin_bit_cast(uint32_t, v);
    return (u + 0x7FFFu + ((u >> 16) & 1u)) >> 16;
}

// Split gate_w fp32 -> bf16 hi/lo in MFMA-B-fragment-swizzled layout:
// chunk index ((ntile*128 + s)*64 + lane) holds, for lane l:
//   w[e = ntile*16 + (l&15)][k = s*32 + (l>>4)*8 + j], j=0..7  (16 B contiguous)
__global__ __launch_bounds__(256) void prep_w_kernel(
    const float* __restrict__ w, short* __restrict__ w_hi, short* __restrict__ w_lo)
{
    int tid  = blockIdx.x * 256 + threadIdx.x;   // 0..32767
    int lane = tid & 63;
    int s    = (tid >> 6) & (kSteps - 1);
    int nt   = tid >> 13;                        // 0..3
    int e = nt * 16 + (lane & 15);
    int k = s * 32 + (lane >> 4) * 8;
    const float* src = w + (size_t)e * kD + k;
    short8 hi, lo;
#pragma unroll
    for (int j = 0; j < 8; ++j) {
        float xv = src[j];
        uint32_t u  = __builtin_bit_cast(uint32_t, xv);
        uint32_t rh = (u + 0x7FFFu + ((u >> 16) & 1u)) & 0xFFFF0000u;
        hi[j] = (short)(rh >> 16);
        float lf = xv - __builtin_bit_cast(float, rh);   // exact residual
        lo[j] = (short)bf16_rne(lf);
    }
    ((short8*)w_hi)[tid] = hi;
    ((short8*)w_lo)[tid] = lo;
}

// Block: 16 rows x 64 experts. 16 waves; wave w = K-chunk w (8 steps of 32).
// Each wave computes all 4 expert N-tiles (x converted ONCE per element).
// Grid: 512 blocks; 1024 thr/block -> up to 16 waves/CU.
__global__ __launch_bounds__(1024, 4) void router_kernel(
    const float* __restrict__ x, const short8* __restrict__ w_hi,
    const short8* __restrict__ w_lo, const float* __restrict__ temp,
    float* __restrict__ out_mat, float* __restrict__ out_idx)
{
    const int lane = threadIdx.x & 63;
    const int wv   = threadIdx.x >> 6;   // K-chunk 0..15
    const int quad = lane >> 4;
    const int mr   = lane & 15;
    const int row0 = blockIdx.x * 16;

    // A frag: lane holds x[row0+mr][k0 + i*32 + quad*8 .. +8]
    const float* xp = x + (size_t)(row0 + mr) * kD
                        + wv * (kStepsPerChunk * 32) + quad * 8;

    f32x4 acc[4];
#pragma unroll
    for (int nt = 0; nt < 4; ++nt) acc[nt] = (f32x4){0.f, 0.f, 0.f, 0.f};

#pragma unroll 2
    for (int i = 0; i < kStepsPerChunk; ++i) {
        const f32x4* ap = (const f32x4*)(xp + i * 32);
        f32x4 a0 = ap[0];
        f32x4 a1 = ap[1];
        short8 ah, al;
#pragma unroll
        for (int j = 0; j < 4; ++j) {
            float xv = a0[j];
            uint32_t u  = __builtin_bit_cast(uint32_t, xv);
            uint32_t rh = (u + 0x7FFFu + ((u >> 16) & 1u)) & 0xFFFF0000u;
            ah[j] = (short)(rh >> 16);
            al[j] = (short)bf16_rne(xv - __builtin_bit_cast(float, rh));
            float yv = a1[j];
            uint32_t u2  = __builtin_bit_cast(uint32_t, yv);
            uint32_t rh2 = (u2 + 0x7FFFu + ((u2 >> 16) & 1u)) & 0xFFFF0000u;
            ah[j + 4] = (short)(rh2 >> 16);
            al[j + 4] = (short)bf16_rne(yv - __builtin_bit_cast(float, rh2));
        }
        const int sbase = (wv * kStepsPerChunk + i) * 64 + lane;
#pragma unroll
        for (int nt = 0; nt < 4; ++nt) {
            short8 wh_ = w_hi[(size_t)(nt * kSteps) * 64 + sbase];
            short8 wl_ = w_lo[(size_t)(nt * kSteps) * 64 + sbase];
            // smallest terms first (same order as the passing R1 kernel)
            acc[nt] = __builtin_amdgcn_mfma_f32_16x16x32_bf16(al, wl_, acc[nt], 0, 0, 0);
            acc[nt] = __builtin_amdgcn_mfma_f32_16x16x32_bf16(al, wh_, acc[nt], 0, 0, 0);
            acc[nt] = __builtin_amdgcn_mfma_f32_16x16x32_bf16(ah, wl_, acc[nt], 0, 0, 0);
            acc[nt] = __builtin_amdgcn_mfma_f32_16x16x32_bf16(ah, wh_, acc[nt], 0, 0, 0);
        }
    }

    // Partial-sum reduction across the 16 K-chunks via LDS.
    // C layout (m89-verified): row_in_tile = quad*4 + reg, col_in_tile = mr.
    __shared__ float part[kChunks * 16 * kE];   // 64 KB
#pragma unroll
    for (int nt = 0; nt < 4; ++nt)
#pragma unroll
        for (int r = 0; r < 4; ++r)
            part[(wv * 16 + quad * 4 + r) * kE + nt * 16 + mr] = acc[nt][r];
    __syncthreads();

    // Thread t: row = t>>6 (== wv), col = t&63 (== lane).
    // So wave r holds row r's 64 logits, one per lane.
    const int row = wv;
    float v = 0.f;
#pragma unroll
    for (int kc = 0; kc < kChunks; ++kc)        // ascending K order: deterministic
        v += part[(kc * 16 + row) * kE + lane];

    // Wave-wide top-2 argmax butterfly; tie-break = lowest index (jax top_k).
    float v1 = v; int i1 = lane;
#pragma unroll
    for (int m = 1; m < 64; m <<= 1) {
        float ov = __shfl_xor(v1, m, 64);
        int   oi = __shfl_xor(i1, m, 64);
        if (ov > v1 || (ov == v1 && oi < i1)) { v1 = ov; i1 = oi; }
    }
    float vm = (lane == i1) ? -3.0e38f : v;
    float v2 = vm; int i2 = lane;
#pragma unroll
    for (int m = 1; m < 64; m <<= 1) {
        float ov = __shfl_xor(v2, m, 64);
        int   oi = __shfl_xor(i2, m, 64);
        if (ov > v2 || (ov == v2 && oi < i2)) { v2 = ov; i2 = oi; }
    }

    float invT = 1.0f / temp[0];
    float e  = expf((v2 - v1) * invT);   // max-subtracted softmax, same as R1
    float sm = 1.0f + e;
    float w1 = 1.0f / sm;
    float w2 = e / sm;

    // Routing-matrix row write: 64 lanes -> 256 B contiguous per wave.
    out_mat[(size_t)(row0 + row) * kE + lane] = (lane == i1) ? w1
                                              : ((lane == i2) ? w2 : 0.0f);
    if (lane == 0) {
        ((float2*)out_idx)[row0 + row] = make_float2((float)i1, (float)i2);
    }
}

extern "C" void kernel_launch(void* const* d_in, const int* in_sizes, int n_in,
                              void* d_out, int out_size, void* d_ws, size_t ws_size,
                              hipStream_t stream) {
    const float* x    = (const float*)d_in[0];
    const float* gw   = (const float*)d_in[1];
    const float* temp = (const float*)d_in[2];

    float* out_mat = (float*)d_out;                      // [8192,64] fp32
    float* out_idx = (float*)d_out + (size_t)kB * kE;    // [8192,2] idx as float

    short* w_hi = (short*)d_ws;                          // 512 KB
    short* w_lo = w_hi + (size_t)kE * kD;                // 512 KB

    prep_w_kernel<<<128, 256, 0, stream>>>(gw, w_hi, w_lo);

    router_kernel<<<kB / 16, 1024, 0, stream>>>(
        x, (const short8*)w_hi, (const short8*)w_lo, temp, out_mat, out_idx);
}

// Round 3
// 213.517 us; speedup vs baseline: 1.2196x; 1.0236x over previous
//
#include <hip/hip_runtime.h>
#include <stdint.h>
#include <stddef.h>

// DynamicRouter: logits = x @ W^T / T; top-2; softmax; scatter.
// B=8192, D=4096, E=64, K=2.
// R3: deep MLP. 8 waves/block (K-chunks of 16 steps), register double-buffered
// x prefetch (next 2-step group issued before current group's compute), reg cap
// 128 via launch_bounds(512,4) -> 2 blocks/CU. 32 KB LDS epilogue.

typedef __attribute__((ext_vector_type(8))) short short8;   // 8 bf16 (4 VGPRs)
typedef __attribute__((ext_vector_type(4))) float f32x4;    // MFMA accumulator

static constexpr int kB = 8192;
static constexpr int kD = 4096;
static constexpr int kE = 64;
static constexpr int kSteps = kD / 32;      // 128 K-steps of 32
static constexpr int kWv = 8;               // waves per block = K-chunks
static constexpr int kSPC = kSteps / kWv;   // 16 steps per chunk
static constexpr int kRows = 16;            // rows per block

__device__ __forceinline__ uint32_t bf16_rne(float v) {
    uint32_t u = __builtin_bit_cast(uint32_t, v);
    return (u + 0x7FFFu + ((u >> 16) & 1u)) >> 16;
}

// fp32x8 -> bf16 hi/lo split (hi RNE; lo = RNE(exact residual))
__device__ __forceinline__ void cvt8(const f32x4& a0, const f32x4& a1,
                                     short8& ah, short8& al) {
#pragma unroll
    for (int j = 0; j < 4; ++j) {
        float xv = a0[j];
        uint32_t u  = __builtin_bit_cast(uint32_t, xv);
        uint32_t rh = (u + 0x7FFFu + ((u >> 16) & 1u)) & 0xFFFF0000u;
        ah[j] = (short)(rh >> 16);
        al[j] = (short)bf16_rne(xv - __builtin_bit_cast(float, rh));
        float yv = a1[j];
        uint32_t u2  = __builtin_bit_cast(uint32_t, yv);
        uint32_t rh2 = (u2 + 0x7FFFu + ((u2 >> 16) & 1u)) & 0xFFFF0000u;
        ah[j + 4] = (short)(rh2 >> 16);
        al[j + 4] = (short)bf16_rne(yv - __builtin_bit_cast(float, rh2));
    }
}

// Split gate_w fp32 -> bf16 hi/lo in MFMA-B-fragment-swizzled layout:
// chunk index ((ntile*128 + s)*64 + lane) holds, for lane l:
//   w[e = ntile*16 + (l&15)][k = s*32 + (l>>4)*8 + j], j=0..7  (16 B contiguous)
__global__ __launch_bounds__(256) void prep_w_kernel(
    const float* __restrict__ w, short* __restrict__ w_hi, short* __restrict__ w_lo)
{
    int tid  = blockIdx.x * 256 + threadIdx.x;   // 0..32767
    int lane = tid & 63;
    int s    = (tid >> 6) & (kSteps - 1);
    int nt   = tid >> 13;                        // 0..3
    int e = nt * 16 + (lane & 15);
    int k = s * 32 + (lane >> 4) * 8;
    const float* src = w + (size_t)e * kD + k;
    short8 hi, lo;
#pragma unroll
    for (int j = 0; j < 8; ++j) {
        float xv = src[j];
        uint32_t u  = __builtin_bit_cast(uint32_t, xv);
        uint32_t rh = (u + 0x7FFFu + ((u >> 16) & 1u)) & 0xFFFF0000u;
        hi[j] = (short)(rh >> 16);
        float lf = xv - __builtin_bit_cast(float, rh);   // exact residual
        lo[j] = (short)bf16_rne(lf);
    }
    ((short8*)w_hi)[tid] = hi;
    ((short8*)w_lo)[tid] = lo;
}

// Block: 16 rows x 64 experts, 8 waves; wave w = K-chunk w (16 steps of 32).
// Register-double-buffered x prefetch (2-step groups). Grid 512.
__global__ __launch_bounds__(512, 4) void router_kernel(
    const float* __restrict__ x, const short8* __restrict__ w_hi,
    const short8* __restrict__ w_lo, const float* __restrict__ temp,
    float* __restrict__ out_mat, float* __restrict__ out_idx)
{
    const int lane = threadIdx.x & 63;
    const int wv   = threadIdx.x >> 6;   // K-chunk 0..7
    const int quad = lane >> 4;
    const int mr   = lane & 15;
    const int row0 = blockIdx.x * kRows;

    // A frag: lane holds x[row0+mr][wv*512 + step*32 + quad*8 .. +8]
    const float* xp = x + (size_t)(row0 + mr) * kD + wv * (kSPC * 32) + quad * 8;

    f32x4 acc[4];
#pragma unroll
    for (int nt = 0; nt < 4; ++nt) acc[nt] = (f32x4){0.f, 0.f, 0.f, 0.f};

    // double-buffered 2-step x groups: 8 groups of 2 steps
    f32x4 xb[2][2][2];   // [buf][st][half]
#pragma unroll
    for (int st = 0; st < 2; ++st) {
        const f32x4* ap = (const f32x4*)(xp + st * 32);
        xb[0][st][0] = ap[0];
        xb[0][st][1] = ap[1];
    }

    for (int g = 0; g < kSPC / 2; ++g) {
        const int cur = g & 1, nxt = cur ^ 1;
        if (g + 1 < kSPC / 2) {   // prefetch next group before any compute
#pragma unroll
            for (int st = 0; st < 2; ++st) {
                const f32x4* ap = (const f32x4*)(xp + ((g + 1) * 2 + st) * 32);
                xb[nxt][st][0] = ap[0];
                xb[nxt][st][1] = ap[1];
            }
        }
#pragma unroll
        for (int st = 0; st < 2; ++st) {
            short8 ah, al;
            cvt8(xb[cur][st][0], xb[cur][st][1], ah, al);
            const size_t sb = (size_t)(wv * kSPC + g * 2 + st) * 64 + lane;
#pragma unroll
            for (int nt = 0; nt < 4; ++nt) {
                short8 wh_ = w_hi[(size_t)(nt * kSteps) * 64 + sb];
                short8 wl_ = w_lo[(size_t)(nt * kSteps) * 64 + sb];
                // smallest terms first (same order as passing R1/R2 kernels)
                acc[nt] = __builtin_amdgcn_mfma_f32_16x16x32_bf16(al, wl_, acc[nt], 0, 0, 0);
                acc[nt] = __builtin_amdgcn_mfma_f32_16x16x32_bf16(al, wh_, acc[nt], 0, 0, 0);
                acc[nt] = __builtin_amdgcn_mfma_f32_16x16x32_bf16(ah, wl_, acc[nt], 0, 0, 0);
                acc[nt] = __builtin_amdgcn_mfma_f32_16x16x32_bf16(ah, wh_, acc[nt], 0, 0, 0);
            }
        }
    }

    // Partial-sum reduction across the 8 K-chunks via LDS (32 KB).
    // C layout (m89-verified): row_in_tile = quad*4 + reg, col = mr.
    __shared__ float part[kWv][kRows][kE];
#pragma unroll
    for (int nt = 0; nt < 4; ++nt)
#pragma unroll
        for (int r = 0; r < 4; ++r)
            part[wv][quad * 4 + r][nt * 16 + mr] = acc[nt][r];
    __syncthreads();

    const float invT = 1.0f / temp[0];
#pragma unroll
    for (int p = 0; p < 2; ++p) {
        const int row = wv + p * kWv;   // wave handles rows wv and wv+8
        float v = 0.f;
#pragma unroll
        for (int s = 0; s < kWv; ++s)   // ascending K order: deterministic
            v += part[s][row][lane];

        // Wave-wide top-2 butterfly; tie-break = lowest index (jax top_k).
        float v1 = v; int i1 = lane;
#pragma unroll
        for (int m = 1; m < 64; m <<= 1) {
            float ov = __shfl_xor(v1, m, 64);
            int   oi = __shfl_xor(i1, m, 64);
            if (ov > v1 || (ov == v1 && oi < i1)) { v1 = ov; i1 = oi; }
        }
        float vm = (lane == i1) ? -3.0e38f : v;
        float v2 = vm; int i2 = lane;
#pragma unroll
        for (int m = 1; m < 64; m <<= 1) {
            float ov = __shfl_xor(v2, m, 64);
            int   oi = __shfl_xor(i2, m, 64);
            if (ov > v2 || (ov == v2 && oi < i2)) { v2 = ov; i2 = oi; }
        }

        float e  = expf((v2 - v1) * invT);   // max-subtracted softmax
        float sm = 1.0f + e;
        out_mat[(size_t)(row0 + row) * kE + lane] =
            (lane == i1) ? (1.0f / sm) : ((lane == i2) ? (e / sm) : 0.0f);
        if (lane == 0)
            ((float2*)out_idx)[row0 + row] = make_float2((float)i1, (float)i2);
    }
}

extern "C" void kernel_launch(void* const* d_in, const int* in_sizes, int n_in,
                              void* d_out, int out_size, void* d_ws, size_t ws_size,
                              hipStream_t stream) {
    const float* x    = (const float*)d_in[0];
    const float* gw   = (const float*)d_in[1];
    const float* temp = (const float*)d_in[2];

    float* out_mat = (float*)d_out;                      // [8192,64] fp32
    float* out_idx = (float*)d_out + (size_t)kB * kE;    // [8192,2] idx as float

    short* w_hi = (short*)d_ws;                          // 512 KB
    short* w_lo = w_hi + (size_t)kE * kD;                // 512 KB

    prep_w_kernel<<<128, 256, 0, stream>>>(gw, w_hi, w_lo);

    router_kernel<<<kB / kRows, 512, 0, stream>>>(
        x, (const short8*)w_hi, (const short8*)w_lo, temp, out_mat, out_idx);
}

// Round 4
// 204.300 us; speedup vs baseline: 1.2746x; 1.0451x over previous
//
#include <hip/hip_runtime.h>
#include <stdint.h>
#include <stddef.h>

// DynamicRouter: logits = x @ W^T / T; top-2; softmax; scatter.
// B=8192, D=4096, E=64, K=2.
// R4: global_load_lds(16B) double-buffered x staging (BK=256, 16 rows), one
// barrier per buffer -> ~16KB/block HBM loads in flight (Little's law needs
// ~9.2KB/CU for 6.3 TB/s). w-frags register-prefetched one buffer ahead.
// part[] reduction overlaid on x LDS (33KB total). Split-bf16 4-term MFMA.

typedef __attribute__((ext_vector_type(8))) short short8;   // 8 bf16 (4 VGPRs)
typedef __attribute__((ext_vector_type(4))) float f32x4;    // MFMA accumulator

static constexpr int kB = 8192;
static constexpr int kD = 4096;
static constexpr int kE = 64;
static constexpr int kSteps = kD / 32;      // 128 K-steps of 32
static constexpr int kWv = 8;               // waves per block
static constexpr int kRows = 16;            // rows per block
static constexpr int kBK = 256;             // K per buffer (8 waves x 32)
static constexpr int kBufs = kD / kBK;      // 16 buffers
static constexpr int kRowPad = 260;         // 256 + 4 floats: stride%32=4 -> 2-way banks (free)

__device__ __forceinline__ uint32_t bf16_rne(float v) {
    uint32_t u = __builtin_bit_cast(uint32_t, v);
    return (u + 0x7FFFu + ((u >> 16) & 1u)) >> 16;
}

// fp32x8 -> bf16 hi/lo split (hi RNE; lo = RNE(exact residual))
__device__ __forceinline__ void cvt8(const f32x4& a0, const f32x4& a1,
                                     short8& ah, short8& al) {
#pragma unroll
    for (int j = 0; j < 4; ++j) {
        float xv = a0[j];
        uint32_t u  = __builtin_bit_cast(uint32_t, xv);
        uint32_t rh = (u + 0x7FFFu + ((u >> 16) & 1u)) & 0xFFFF0000u;
        ah[j] = (short)(rh >> 16);
        al[j] = (short)bf16_rne(xv - __builtin_bit_cast(float, rh));
        float yv = a1[j];
        uint32_t u2  = __builtin_bit_cast(uint32_t, yv);
        uint32_t rh2 = (u2 + 0x7FFFu + ((u2 >> 16) & 1u)) & 0xFFFF0000u;
        ah[j + 4] = (short)(rh2 >> 16);
        al[j + 4] = (short)bf16_rne(yv - __builtin_bit_cast(float, rh2));
    }
}

// async 16B global->LDS; LDS dest is wave-uniform base + lane*16 (HW rule).
__device__ __forceinline__ void glds16(const float* g, float* l) {
    __builtin_amdgcn_global_load_lds(
        (const __attribute__((address_space(1))) unsigned int*)g,
        (__attribute__((address_space(3))) unsigned int*)l, 16, 0, 0);
}

// Split gate_w fp32 -> bf16 hi/lo in MFMA-B-fragment-swizzled layout:
// chunk index ((ntile*128 + s)*64 + lane) holds, for lane l:
//   w[e = ntile*16 + (l&15)][k = s*32 + (l>>4)*8 + j], j=0..7  (16 B contiguous)
__global__ __launch_bounds__(256) void prep_w_kernel(
    const float* __restrict__ w, short* __restrict__ w_hi, short* __restrict__ w_lo)
{
    int tid  = blockIdx.x * 256 + threadIdx.x;   // 0..32767
    int lane = tid & 63;
    int s    = (tid >> 6) & (kSteps - 1);
    int nt   = tid >> 13;                        // 0..3
    int e = nt * 16 + (lane & 15);
    int k = s * 32 + (lane >> 4) * 8;
    const float* src = w + (size_t)e * kD + k;
    short8 hi, lo;
#pragma unroll
    for (int j = 0; j < 8; ++j) {
        float xv = src[j];
        uint32_t u  = __builtin_bit_cast(uint32_t, xv);
        uint32_t rh = (u + 0x7FFFu + ((u >> 16) & 1u)) & 0xFFFF0000u;
        hi[j] = (short)(rh >> 16);
        float lf = xv - __builtin_bit_cast(float, rh);   // exact residual
        lo[j] = (short)bf16_rne(lf);
    }
    ((short8*)w_hi)[tid] = hi;
    ((short8*)w_lo)[tid] = lo;
}

// Block: 16 rows x 64 experts, 8 waves. K-loop over 16 buffers of BK=256;
// wave wv computes step (b*8+wv) each buffer; x staged in LDS by glds16.
__global__ __launch_bounds__(512, 4) void router_kernel(
    const float* __restrict__ x, const short8* __restrict__ w_hi,
    const short8* __restrict__ w_lo, const float* __restrict__ temp,
    float* __restrict__ out_mat, float* __restrict__ out_idx)
{
    const int lane = threadIdx.x & 63;
    const int wv   = threadIdx.x >> 6;   // 0..7
    const int quad = lane >> 4;
    const int mr   = lane & 15;
    const int row0 = blockIdx.x * kRows;

    // LDS union: x double-buffer (2*16*260 fl = 33280 B) / part (8192 fl)
    __shared__ __align__(16) float smem[2 * kRows * kRowPad];
    float (*lds_x)[kRows][kRowPad] = (float (*)[kRows][kRowPad])smem;
    float (*part)[kRows][kE]       = (float (*)[kRows][kE])smem;

    f32x4 acc[4];
#pragma unroll
    for (int nt = 0; nt < 4; ++nt) acc[nt] = (f32x4){0.f, 0.f, 0.f, 0.f};

    short8 wbh[2][4], wbl[2][4];

    // Prologue: issue buf0 fill (rows 2wv, 2wv+1) + w-frags for step wv.
#pragma unroll
    for (int seg = 0; seg < 2; ++seg) {
        const int r = 2 * wv + seg;
        glds16(x + (size_t)(row0 + r) * kD + lane * 4, &lds_x[0][r][0]);
    }
#pragma unroll
    for (int nt = 0; nt < 4; ++nt) {
        wbh[0][nt] = w_hi[(size_t)(nt * kSteps + wv) * 64 + lane];
        wbl[0][nt] = w_lo[(size_t)(nt * kSteps + wv) * 64 + lane];
    }

#pragma unroll 2
    for (int b = 0; b < kBufs; ++b) {
        const int pb = b & 1;
        __syncthreads();   // drains glds for buf b (and w-frag loads for step b)

        if (b + 1 < kBufs) {   // issue buf b+1 fill + w-frags for step b+1
#pragma unroll
            for (int seg = 0; seg < 2; ++seg) {
                const int r = 2 * wv + seg;
                glds16(x + (size_t)(row0 + r) * kD + (b + 1) * kBK + lane * 4,
                       &lds_x[pb ^ 1][r][0]);
            }
            const int s = (b + 1) * kWv + wv;
#pragma unroll
            for (int nt = 0; nt < 4; ++nt) {
                wbh[pb ^ 1][nt] = w_hi[(size_t)(nt * kSteps + s) * 64 + lane];
                wbl[pb ^ 1][nt] = w_lo[(size_t)(nt * kSteps + s) * 64 + lane];
            }
        }

        // A frag from LDS: x[row0+mr][b*256 + wv*32 + quad*8 + 0..8)
        const float* ap = &lds_x[pb][mr][wv * 32 + quad * 8];
        f32x4 a0 = *(const f32x4*)ap;
        f32x4 a1 = *(const f32x4*)(ap + 4);
        short8 ah, al;
        cvt8(a0, a1, ah, al);
#pragma unroll
        for (int nt = 0; nt < 4; ++nt) {
            // smallest terms first (same order as passing R1-R3 kernels)
            acc[nt] = __builtin_amdgcn_mfma_f32_16x16x32_bf16(al, wbl[pb][nt], acc[nt], 0, 0, 0);
            acc[nt] = __builtin_amdgcn_mfma_f32_16x16x32_bf16(al, wbh[pb][nt], acc[nt], 0, 0, 0);
            acc[nt] = __builtin_amdgcn_mfma_f32_16x16x32_bf16(ah, wbl[pb][nt], acc[nt], 0, 0, 0);
            acc[nt] = __builtin_amdgcn_mfma_f32_16x16x32_bf16(ah, wbh[pb][nt], acc[nt], 0, 0, 0);
        }
    }

    __syncthreads();   // protect lds_x readers before overlaying part[]

    // Partial-sum reduction across the 8 waves' K-interleaved chunks.
    // C layout (m89-verified): row_in_tile = quad*4 + reg, col = mr.
#pragma unroll
    for (int nt = 0; nt < 4; ++nt)
#pragma unroll
        for (int r = 0; r < 4; ++r)
            part[wv][quad * 4 + r][nt * 16 + mr] = acc[nt][r];
    __syncthreads();

    const float invT = 1.0f / temp[0];
#pragma unroll
    for (int p = 0; p < 2; ++p) {
        const int row = wv + p * kWv;   // wave handles rows wv and wv+8
        float v = 0.f;
#pragma unroll
        for (int s = 0; s < kWv; ++s)   // ascending wave index: deterministic
            v += part[s][row][lane];

        // Wave-wide top-2 butterfly; tie-break = lowest index (jax top_k).
        float v1 = v; int i1 = lane;
#pragma unroll
        for (int m = 1; m < 64; m <<= 1) {
            float ov = __shfl_xor(v1, m, 64);
            int   oi = __shfl_xor(i1, m, 64);
            if (ov > v1 || (ov == v1 && oi < i1)) { v1 = ov; i1 = oi; }
        }
        float vm = (lane == i1) ? -3.0e38f : v;
        float v2 = vm; int i2 = lane;
#pragma unroll
        for (int m = 1; m < 64; m <<= 1) {
            float ov = __shfl_xor(v2, m, 64);
            int   oi = __shfl_xor(i2, m, 64);
            if (ov > v2 || (ov == v2 && oi < i2)) { v2 = ov; i2 = oi; }
        }

        float e  = expf((v2 - v1) * invT);   // max-subtracted softmax
        float sm = 1.0f + e;
        out_mat[(size_t)(row0 + row) * kE + lane] =
            (lane == i1) ? (1.0f / sm) : ((lane == i2) ? (e / sm) : 0.0f);
        if (lane == 0)
            ((float2*)out_idx)[row0 + row] = make_float2((float)i1, (float)i2);
    }
}

extern "C" void kernel_launch(void* const* d_in, const int* in_sizes, int n_in,
                              void* d_out, int out_size, void* d_ws, size_t ws_size,
                              hipStream_t stream) {
    const float* x    = (const float*)d_in[0];
    const float* gw   = (const float*)d_in[1];
    const float* temp = (const float*)d_in[2];

    float* out_mat = (float*)d_out;                      // [8192,64] fp32
    float* out_idx = (float*)d_out + (size_t)kB * kE;    // [8192,2] idx as float

    short* w_hi = (short*)d_ws;                          // 512 KB
    short* w_lo = w_hi + (size_t)kE * kD;                // 512 KB

    prep_w_kernel<<<128, 256, 0, stream>>>(gw, w_hi, w_lo);

    router_kernel<<<kB / kRows, 512, 0, stream>>>(
        x, (const short8*)w_hi, (const short8*)w_lo, temp, out_mat, out_idx);
}